// Round 1
// baseline (1736.262 us; speedup 1.0000x reference)
//
#include <hip/hip_runtime.h>
#include <hip/hip_bf16.h>
#include <math.h>

#define Bd 2
#define Td 2048
#define Hd 16
#define Sd 64
#define Ed 1024
#define Fd 4096

typedef __attribute__((ext_vector_type(8))) short short8;
typedef __attribute__((ext_vector_type(4))) float f32x4;
typedef __hip_bfloat16 bf16;

__device__ __forceinline__ unsigned short f2bfu(float f){
  bf16 h = __float2bfloat16(f);
  unsigned short u;
  __builtin_memcpy(&u, &h, 2);
  return u;
}

// ---------------- f32 -> bf16 conversion (grid-stride over float4) ----------------
__global__ __launch_bounds__(256) void cvt_bf16_kernel(const float* __restrict__ src,
                                                       bf16* __restrict__ dst, int n4){
  int i = blockIdx.x*256 + threadIdx.x;
  int stride = gridDim.x*256;
  for (; i < n4; i += stride){
    float4 v = ((const float4*)src)[i];
    bf16* d = dst + (size_t)i*4;
    d[0] = __float2bfloat16(v.x);
    d[1] = __float2bfloat16(v.y);
    d[2] = __float2bfloat16(v.z);
    d[3] = __float2bfloat16(v.w);
  }
}

// ---------------- kqv projection: x[b,t,:] x kqv_w[o,s] -> k,q,v bf16 [B,T,H,S] ----------------
__global__ __launch_bounds__(192) void kqv_kernel(const float* __restrict__ x, const float* __restrict__ w,
    bf16* __restrict__ kb, bf16* __restrict__ qb, bf16* __restrict__ vb){
  __shared__ float xs[Ed];
  int bt = blockIdx.x;
  int o = threadIdx.x;            // 0..191 : output channel of kqv_w
  const float* xrow = x + (size_t)bt*Ed;
  for (int i = o; i < Ed; i += 192) xs[i] = xrow[i];
  __syncthreads();
  float4 wr[16];
  const float4* w4 = (const float4*)(w + o*Sd);
  #pragma unroll
  for (int i = 0; i < 16; i++) wr[i] = w4[i];
  int part = o >> 6, sidx = o & 63;          // split order: k, q, v
  bf16* ob = (part == 0) ? kb : (part == 1 ? qb : vb);
  ob += (size_t)bt*Hd*Sd + sidx;
  for (int h = 0; h < Hd; h++){
    const float4* xh4 = (const float4*)(xs + h*Sd);
    float a0=0.f,a1=0.f,a2=0.f,a3=0.f;
    #pragma unroll
    for (int i = 0; i < 16; i++){
      float4 xv = xh4[i];   // LDS broadcast (all lanes same addr)
      a0 = fmaf(xv.x, wr[i].x, a0);
      a1 = fmaf(xv.y, wr[i].y, a1);
      a2 = fmaf(xv.z, wr[i].z, a2);
      a3 = fmaf(xv.w, wr[i].w, a3);
    }
    ob[h*Sd] = __float2bfloat16((a0+a1)+(a2+a3));
  }
}

// ---------------- transpose v [B,T,H,S] -> vt [B,H,S,T] ----------------
__global__ __launch_bounds__(256) void vt_kernel(const bf16* __restrict__ vb, bf16* __restrict__ vt){
  __shared__ bf16 tile[64][72];
  int t0 = blockIdx.x*64, h = blockIdx.y, b = blockIdx.z;
  int tid = threadIdx.x;
  for (int i = tid; i < 4096; i += 256){
    int tt = i >> 6, s = i & 63;
    tile[tt][s] = vb[(((size_t)b*Td + t0 + tt)*Hd + h)*Sd + s];
  }
  __syncthreads();
  for (int i = tid; i < 4096; i += 256){
    int s = i >> 6, tt = i & 63;
    vt[(((size_t)b*Hd + h)*Sd + s)*Td + t0 + tt] = tile[tt][s];
  }
}

// ---------------- Pass A: scores = qk^T/8 + prev -> att_score (d_out), online row stats (m,l) ----------------
// block = 1024 thr = 16 waves, wave w <-> head w. grid = (T/16, B)
__global__ __launch_bounds__(1024) void attn_score_kernel(
    const bf16* __restrict__ qb, const bf16* __restrict__ kb,
    const float* __restrict__ prev, float* __restrict__ att,
    float* __restrict__ m_ws, float* __restrict__ linv_ws){
  int i0 = blockIdx.x*16, b = blockIdx.y;
  int tid = threadIdx.x;
  int wid = tid >> 6, lane = tid & 63, col = lane & 15, quad = lane >> 4;
  __shared__ float Ss[16][16][17];          // [head][row i][col j]
  __shared__ float Mp[4][16][16];           // partial stats [jq][ii][h]
  __shared__ float Lp[4][16][16];

  // A-frag: A[m=col][k=quad*8+j] ; rows are q rows i0+col, k over S
  const bf16* qbase = qb + (((size_t)b*Td + i0 + col)*Hd + wid)*Sd + quad*8;
  short8 aq0 = *(const short8*)(qbase);
  short8 aq1 = *(const short8*)(qbase + 32);

  int ii = tid >> 6, jq = (tid >> 4) & 3, h2 = tid & 15;   // writeout decode
  float m_t = -1e30f, l_t = 0.f;

  for (int jt = 0; jt < Td/16; jt++){
    int j0 = jt*16;
    // B-frag: B[k=quad*8+j][n=col] = K[j0+col][s=quad*8+j]
    const bf16* kbase = kb + (((size_t)b*Td + j0 + col)*Hd + wid)*Sd + quad*8;
    short8 bk0 = *(const short8*)(kbase);
    short8 bk1 = *(const short8*)(kbase + 32);
    f32x4 acc = {0.f, 0.f, 0.f, 0.f};
    acc = __builtin_amdgcn_mfma_f32_16x16x32_bf16(aq0, bk0, acc, 0, 0, 0);
    acc = __builtin_amdgcn_mfma_f32_16x16x32_bf16(aq1, bk1, acc, 0, 0, 0);
    #pragma unroll
    for (int r = 0; r < 4; r++) Ss[wid][quad*4 + r][col] = acc[r];   // D: row=quad*4+r, col=lane&15
    __syncthreads();
    {
      size_t gb = (((size_t)b*Td + i0 + ii)*Td + j0 + jq*4)*Hd + h2;
      float v0 = Ss[h2][ii][jq*4+0]*0.125f + prev[gb];
      float v1 = Ss[h2][ii][jq*4+1]*0.125f + prev[gb + Hd];
      float v2 = Ss[h2][ii][jq*4+2]*0.125f + prev[gb + 2*Hd];
      float v3 = Ss[h2][ii][jq*4+3]*0.125f + prev[gb + 3*Hd];
      att[gb]        = v0;
      att[gb + Hd]   = v1;
      att[gb + 2*Hd] = v2;
      att[gb + 3*Hd] = v3;
      float mx = fmaxf(fmaxf(v0, v1), fmaxf(v2, v3));
      float nm = fmaxf(m_t, mx);
      float sc = __expf(m_t - nm);
      l_t = l_t*sc + __expf(v0-nm) + __expf(v1-nm) + __expf(v2-nm) + __expf(v3-nm);
      m_t = nm;
    }
    __syncthreads();
  }
  Mp[jq][ii][h2] = m_t;
  Lp[jq][ii][h2] = l_t;
  __syncthreads();
  if (jq == 0){
    float m0 = Mp[0][ii][h2], m1 = Mp[1][ii][h2], m2 = Mp[2][ii][h2], m3 = Mp[3][ii][h2];
    float M = fmaxf(fmaxf(m0, m1), fmaxf(m2, m3));
    float L = Lp[0][ii][h2]*__expf(m0-M) + Lp[1][ii][h2]*__expf(m1-M)
            + Lp[2][ii][h2]*__expf(m2-M) + Lp[3][ii][h2]*__expf(m3-M);
    size_t sidx = ((size_t)b*Td + i0 + ii)*Hd + h2;
    m_ws[sidx] = M;
    linv_ws[sidx] = 1.0f / L;
  }
}

// ---------------- Pass B: P = exp(S - m), O = P V, res = O/l -> resb bf16 [B*T, E] ----------------
// block = 1024 thr = 16 waves (head per wave). grid = (T/16, B)
__global__ __launch_bounds__(1024) void attn_av_kernel(
    const float* __restrict__ att, const bf16* __restrict__ vt,
    const float* __restrict__ m_ws, const float* __restrict__ linv_ws,
    bf16* __restrict__ resb){
  int i0 = blockIdx.x*16, b = blockIdx.y;
  int tid = threadIdx.x;
  int wid = tid >> 6, lane = tid & 63, col = lane & 15, quad = lane >> 4;
  __shared__ __align__(16) bf16 Ps[16][17][40];   // [head][i][j 0..31 + pad]
  __shared__ float Msh[16][16], Lsh[16][16];      // [i][h]
  if (tid < 256){
    int ri = tid >> 4, rh = tid & 15;
    size_t sidx = ((size_t)b*Td + i0 + ri)*Hd + rh;
    Msh[ri][rh] = m_ws[sidx];
    Lsh[ri][rh] = linv_ws[sidx];
  }
  __syncthreads();
  f32x4 O[4];
  #pragma unroll
  for (int st = 0; st < 4; st++) O[st] = (f32x4){0.f,0.f,0.f,0.f};

  int cii = tid >> 6, co = (tid >> 4) & 3, ch = tid & 15;   // conversion decode
  float mrow = Msh[cii][ch];
  const bf16* vbase = vt + (((size_t)b*Hd + wid)*Sd + col)*Td;

  for (int jt = 0; jt < Td/32; jt++){
    int j0 = jt*32;
    // cooperative load of S tile (coalesced over h), exp, bf16, store to Ps in A-frag layout
    size_t gb = (((size_t)b*Td + i0 + cii)*Td + j0 + co*8)*Hd + ch;
    short8 sv;
    #pragma unroll
    for (int e = 0; e < 8; e++){
      sv[e] = (short)f2bfu(__expf(att[gb + (size_t)e*Hd] - mrow));
    }
    *(short8*)(&Ps[ch][cii][co*8]) = sv;
    __syncthreads();
    // A-frag: P[m=col][k=quad*8+j]
    short8 a = *(const short8*)(&Ps[wid][col][quad*8]);
    #pragma unroll
    for (int st = 0; st < 4; st++){
      // B-frag: V[k=j0+quad*8+j][n = st*16+col] read from vt [B,H,S,T]
      short8 bv = *(const short8*)(vbase + (size_t)st*16*Td + j0 + quad*8);
      O[st] = __builtin_amdgcn_mfma_f32_16x16x32_bf16(a, bv, O[st], 0, 0, 0);
    }
    __syncthreads();
  }
  #pragma unroll
  for (int st = 0; st < 4; st++){
    #pragma unroll
    for (int r = 0; r < 4; r++){
      int irow = quad*4 + r;
      float val = O[st][r] * Lsh[irow][wid];
      resb[((size_t)b*Td + i0 + irow)*Ed + wid*Sd + st*16 + col] = __float2bfloat16(val);
    }
  }
}

// ---------------- bf16 GEMM  C[M,N] = A[M,K] * Bw[N,K]^T  + fused epilogue ----------------
// EPI 0: outf = C + addend            (proj: + x residual)
// EPI 1: outb = gelu_exact(C + bias)  (ff1 -> bf16 hidden)
// EPI 2: outf = C + bias + addend     (ff2: + b2 + x1 residual)
template<int EPI>
__global__ __launch_bounds__(256) void gemm_kernel(
    const bf16* __restrict__ A, const bf16* __restrict__ Bw,
    int M, int N, int K,
    const float* __restrict__ bias, const float* __restrict__ addend,
    float* __restrict__ outf, bf16* __restrict__ outb){
  __shared__ __align__(16) bf16 As[128*32];
  __shared__ __align__(16) bf16 Bs[128*32];
  int tid = threadIdx.x;
  int wid = tid >> 6, lane = tid & 63, col = lane & 15, quad = lane >> 4;
  int n0 = blockIdx.x*128, m0 = blockIdx.y*128;
  int wy = wid >> 1, wx = wid & 1;
  f32x4 acc[4][4];
  #pragma unroll
  for (int i = 0; i < 4; i++)
    #pragma unroll
    for (int j = 0; j < 4; j++) acc[i][j] = (f32x4){0.f,0.f,0.f,0.f};

  int srow = tid >> 2, skc = tid & 3;
  for (int k0 = 0; k0 < K; k0 += 32){
    __syncthreads();
    #pragma unroll
    for (int i = 0; i < 2; i++){
      const bf16* gpa = A + (size_t)(m0 + srow + i*64)*K + k0 + skc*8;
      bf16* lpa = As + ((size_t)i*256 + wid*64)*8;   // wave-uniform base + lane*16B
      __builtin_amdgcn_global_load_lds((const __attribute__((address_space(1))) unsigned int*)gpa,
                                       (__attribute__((address_space(3))) unsigned int*)lpa, 16, 0, 0);
      const bf16* gpb = Bw + (size_t)(n0 + srow + i*64)*K + k0 + skc*8;
      bf16* lpb = Bs + ((size_t)i*256 + wid*64)*8;
      __builtin_amdgcn_global_load_lds((const __attribute__((address_space(1))) unsigned int*)gpb,
                                       (__attribute__((address_space(3))) unsigned int*)lpb, 16, 0, 0);
    }
    __syncthreads();
    short8 af[4], bf_[4];
    #pragma unroll
    for (int t = 0; t < 4; t++){
      af[t]  = *(const short8*)(As + (wy*64 + t*16 + col)*32 + quad*8);
      bf_[t] = *(const short8*)(Bs + (wx*64 + t*16 + col)*32 + quad*8);
    }
    #pragma unroll
    for (int i = 0; i < 4; i++)
      #pragma unroll
      for (int j = 0; j < 4; j++)
        acc[i][j] = __builtin_amdgcn_mfma_f32_16x16x32_bf16(af[i], bf_[j], acc[i][j], 0, 0, 0);
  }
  #pragma unroll
  for (int i = 0; i < 4; i++){
    #pragma unroll
    for (int r = 0; r < 4; r++){
      int mrow = m0 + wy*64 + i*16 + quad*4 + r;
      #pragma unroll
      for (int j = 0; j < 4; j++){
        int ncol = n0 + wx*64 + j*16 + col;
        float v = acc[i][j][r];
        size_t oidx = (size_t)mrow*N + ncol;
        if (EPI == 0){
          outf[oidx] = v + addend[oidx];
        } else if (EPI == 1){
          float t = v + bias[ncol];
          outb[oidx] = __float2bfloat16(0.5f*t*(1.0f + erff(t*0.70710678118f)));
        } else {
          outf[oidx] = v + bias[ncol] + addend[oidx];
        }
      }
    }
  }
}

// ---------------- row LayerNorm over E=1024 ----------------
__global__ __launch_bounds__(256) void ln_kernel(const float* __restrict__ in,
    const float* __restrict__ gw, const float* __restrict__ gb,
    float* __restrict__ outf, bf16* __restrict__ outb){
  int row = blockIdx.x, tid = threadIdx.x;
  const float4* r4 = (const float4*)(in + (size_t)row*Ed);
  float4 xv = r4[tid];
  float s  = xv.x + xv.y + xv.z + xv.w;
  float ss = xv.x*xv.x + xv.y*xv.y + xv.z*xv.z + xv.w*xv.w;
  #pragma unroll
  for (int off = 32; off > 0; off >>= 1){
    s  += __shfl_down(s, off);
    ss += __shfl_down(ss, off);
  }
  __shared__ float sb[4], ssb[4], mv[2];
  int lane = tid & 63, wv = tid >> 6;
  if (lane == 0){ sb[wv] = s; ssb[wv] = ss; }
  __syncthreads();
  if (tid == 0){
    float S  = sb[0]+sb[1]+sb[2]+sb[3];
    float SS = ssb[0]+ssb[1]+ssb[2]+ssb[3];
    float mean = S*(1.0f/Ed);
    float var  = SS*(1.0f/Ed) - mean*mean;
    mv[0] = mean; mv[1] = rsqrtf(var + 1e-5f);
  }
  __syncthreads();
  float mean = mv[0], rstd = mv[1];
  float4 wv4 = ((const float4*)gw)[tid];
  float4 bv4 = ((const float4*)gb)[tid];
  float4 o;
  o.x = (xv.x - mean)*rstd*wv4.x + bv4.x;
  o.y = (xv.y - mean)*rstd*wv4.y + bv4.y;
  o.z = (xv.z - mean)*rstd*wv4.z + bv4.z;
  o.w = (xv.w - mean)*rstd*wv4.w + bv4.w;
  if (outf) ((float4*)(outf + (size_t)row*Ed))[tid] = o;
  if (outb){
    bf16* ob = outb + (size_t)row*Ed + tid*4;
    ob[0] = __float2bfloat16(o.x);
    ob[1] = __float2bfloat16(o.y);
    ob[2] = __float2bfloat16(o.z);
    ob[3] = __float2bfloat16(o.w);
  }
}

extern "C" void kernel_launch(void* const* d_in, const int* in_sizes, int n_in,
                              void* d_out, int out_size, void* d_ws, size_t ws_size,
                              hipStream_t stream){
  (void)in_sizes; (void)n_in; (void)out_size; (void)ws_size;
  const float* x      = (const float*)d_in[0];
  const float* prev   = (const float*)d_in[1];
  const float* kqv_w  = (const float*)d_in[2];
  const float* proj_w = (const float*)d_in[3];
  const float* ln1_w  = (const float*)d_in[4];
  const float* ln1_b  = (const float*)d_in[5];
  const float* ln2_w  = (const float*)d_in[6];
  const float* ln2_b  = (const float*)d_in[7];
  const float* ff_w1  = (const float*)d_in[8];
  const float* ff_b1  = (const float*)d_in[9];
  const float* ff_w2  = (const float*)d_in[10];
  const float* ff_b2  = (const float*)d_in[11];

  float* out_x2  = (float*)d_out;
  float* out_att = out_x2 + (size_t)Bd*Td*Ed;

  char* wsp = (char*)d_ws;
  auto alloc = [&](size_t bytes)->char*{
    char* p = wsp;
    wsp += (bytes + 255) & ~(size_t)255;
    return p;
  };
  const size_t NTOK = (size_t)Bd*Td;            // 4096
  bf16* kb    = (bf16*)alloc(NTOK*Ed*2);        // k  [B,T,H,S]
  bf16* qb    = (bf16*)alloc(NTOK*Ed*2);        // q
  bf16* vb    = (bf16*)alloc(NTOK*Ed*2);        // v
  bf16* vtb   = (bf16*)alloc(NTOK*Ed*2);        // v^T [B,H,S,T]
  bf16* resb  = (bf16*)alloc(NTOK*Ed*2);        // attention out [B*T,E]
  bf16* x1b   = (bf16*)alloc(NTOK*Ed*2);        // x1 bf16
  bf16* hidb  = (bf16*)alloc(NTOK*Fd*2);        // gelu hidden [B*T,4E]
  bf16* pwb   = (bf16*)alloc((size_t)Ed*Ed*2);  // proj_w bf16
  bf16* w1b   = (bf16*)alloc((size_t)Fd*Ed*2);  // ff_w1 bf16
  bf16* w2b   = (bf16*)alloc((size_t)Ed*Fd*2);  // ff_w2 bf16
  float* m_ws    = (float*)alloc(NTOK*Hd*4);
  float* linv_ws = (float*)alloc(NTOK*Hd*4);
  float* sum_ws  = (float*)alloc(NTOK*Ed*4);    // pre-LN sums (reused for both LNs)
  float* x1f     = (float*)alloc(NTOK*Ed*4);    // x1 fp32 (residual for ff2)

  // weight conversions
  cvt_bf16_kernel<<<1024, 256, 0, stream>>>(proj_w, pwb, (Ed*Ed)/4);
  cvt_bf16_kernel<<<4096, 256, 0, stream>>>(ff_w1, w1b, (Fd*Ed)/4);
  cvt_bf16_kernel<<<4096, 256, 0, stream>>>(ff_w2, w2b, (Ed*Fd)/4);

  // kqv + v transpose
  kqv_kernel<<<Bd*Td, 192, 0, stream>>>(x, kqv_w, kb, qb, vb);
  vt_kernel<<<dim3(Td/64, Hd, Bd), 256, 0, stream>>>(vb, vtb);

  // attention
  attn_score_kernel<<<dim3(Td/16, Bd), 1024, 0, stream>>>(qb, kb, prev, out_att, m_ws, linv_ws);
  attn_av_kernel<<<dim3(Td/16, Bd), 1024, 0, stream>>>(out_att, vtb, m_ws, linv_ws, resb);

  // proj + x residual
  gemm_kernel<0><<<dim3(Ed/128, (Bd*Td)/128), 256, 0, stream>>>(
      resb, pwb, Bd*Td, Ed, Ed, nullptr, x, sum_ws, nullptr);
  // LN1 -> x1 (f32 + bf16)
  ln_kernel<<<Bd*Td, 256, 0, stream>>>(sum_ws, ln1_w, ln1_b, x1f, x1b);
  // ff1 + gelu -> hidden bf16
  gemm_kernel<1><<<dim3(Fd/128, (Bd*Td)/128), 256, 0, stream>>>(
      x1b, w1b, Bd*Td, Fd, Ed, ff_b1, nullptr, nullptr, hidb);
  // ff2 + b2 + x1 residual
  gemm_kernel<2><<<dim3(Ed/128, (Bd*Td)/128), 256, 0, stream>>>(
      hidb, w2b, Bd*Td, Ed, Fd, ff_b2, x1f, sum_ws, nullptr);
  // LN2 -> x2
  ln_kernel<<<Bd*Td, 256, 0, stream>>>(sum_ws, ln2_w, ln2_b, out_x2, nullptr);
}